// Round 1
// baseline (166.596 us; speedup 1.0000x reference)
//
#include <hip/hip_runtime.h>
#include <stdint.h>

// MinimumErrorRateLoss: edit-distance (unit costs) via Myers/Hyyrö bit-parallel
// DP, then softmax-weighted centered error-rate mean.
//
// Layout facts (fixed problem size):
//   log_probs: (128, 64) f32      -> lp[b*64+s]
//   ref:       (256, 128) i32     -> ref[j*128+b]   (shared across samples)
//   hyp:       (256, 128, 64) i32 -> hyp[t*8192 + b*64 + s]
//   out:       scalar f32
// EOS = 0, INCLUDE_EOS -> len = first-EOS-idx + 1, else T.

#define BATCH   128
#define SAMPLES 64
#define RLEN    256
#define HLEN    256
#define NSEQ    (BATCH*SAMPLES)
#define NTOK    1000
#define NW      4          // 256 ref positions / 64 bits

typedef unsigned long long u64;

// One block per batch element b (64 threads = 1 wave, one sample per lane).
// PM[token][w] bit j of word w set iff ref[b][w*64+j... ] == token (j < ref_len).
__global__ __launch_bounds__(64) void mer_edit(const int* __restrict__ ref,
                                               const int* __restrict__ hyp,
                                               int* __restrict__ dist,
                                               int* __restrict__ reflen)
{
    const int b   = blockIdx.x;    // 0..127
    const int tid = threadIdx.x;   // 0..63
    const int n   = b * SAMPLES + tid;

    __shared__ u64 pm[NTOK * NW];  // 32000 B

    // ---- ref_len: first EOS in ref column b (wave-reduce min) ----
    int firsteos = RLEN;
#pragma unroll
    for (int k = 0; k < RLEN / 64; k++) {
        int j  = tid + 64 * k;
        int tk = ref[j * BATCH + b];
        if (tk == 0) firsteos = min(firsteos, j);
    }
#pragma unroll
    for (int off = 32; off > 0; off >>= 1)
        firsteos = min(firsteos, __shfl_down(firsteos, off));
    firsteos = __shfl(firsteos, 0);
    const int m = (firsteos < RLEN) ? (firsteos + 1) : RLEN;  // 1..256

    // ---- build PM table in LDS ----
    for (int i = tid; i < NTOK * NW; i += 64) pm[i] = 0ull;
    __syncthreads();
    for (int j = tid; j < m; j += 64) {
        int tk = ref[j * BATCH + b];
        atomicOr((unsigned long long*)&pm[tk * NW + (j >> 6)], 1ull << (j & 63));
    }
    __syncthreads();

    // ---- Myers/Hyyrö bit-parallel Levenshtein ----
    const int sw = (m - 1) >> 6, sb = (m - 1) & 63;  // score bit (wave-uniform)
    u64 VP[NW] = {~0ull, ~0ull, ~0ull, ~0ull};
    u64 VN[NW] = {0, 0, 0, 0};
    int  score = m;
    bool done  = false;

    // software pipeline: global token prefetch 2 ahead, LDS Eq prefetch 1 ahead
    int tokA = hyp[0 * NSEQ + n];
    int tokB = hyp[1 * NSEQ + n];
    u64 EqA[NW];
    {
        const u64* p = &pm[tokA * NW];
        EqA[0] = p[0]; EqA[1] = p[1]; EqA[2] = p[2]; EqA[3] = p[3];
    }

    for (int t = 0; t < HLEN; t++) {
        int t2   = (t + 2 < HLEN) ? (t + 2) : (HLEN - 1);
        int tokC = hyp[t2 * NSEQ + n];
        u64 EqB[NW];
        {
            const u64* p = &pm[tokB * NW];
            EqB[0] = p[0]; EqB[1] = p[1]; EqB[2] = p[2]; EqB[3] = p[3];
        }

        if (!done) {
            u64 addc = 0, hpc = 1ull, hnc = 0;  // hpc=1: D[0][j]=j boundary
            int sdelta = 0;
#pragma unroll
            for (int w = 0; w < NW; w++) {
                u64 eq = EqA[w], vp = VP[w], vn = VN[w];
                u64 x  = eq & vp;
                u64 s1 = x + vp;
                u64 c0 = (u64)(s1 < x);
                u64 s2 = s1 + addc;
                u64 c1 = (u64)(s2 < s1);
                addc   = c0 | c1;
                u64 D0 = (s2 ^ vp) | eq | vn;
                u64 HP = vn | ~(D0 | vp);
                u64 HN = vp & D0;
                if (w == sw)  // uniform branch (m is per-block uniform)
                    sdelta = (int)((HP >> sb) & 1ull) - (int)((HN >> sb) & 1ull);
                u64 nhpc = HP >> 63, nhnc = HN >> 63;
                u64 HPs = (HP << 1) | hpc, HNs = (HN << 1) | hnc;
                hpc = nhpc; hnc = nhnc;
                VP[w] = HNs | ~(D0 | HPs);
                VN[w] = HPs & D0;
            }
            score += sdelta;
            if (tokA == 0) done = true;  // processed first EOS -> freeze
        }

        EqA[0] = EqB[0]; EqA[1] = EqB[1]; EqA[2] = EqB[2]; EqA[3] = EqB[3];
        tokA = tokB; tokB = tokC;
    }

    dist[n] = score;
    if (tid == 0) reflen[b] = m;
}

// Single block, 128 threads: thread b handles batch element b entirely, f64.
// sum_s (er - mean_er)*softmax = dot/sumexp - mean_er   (since sum p = 1)
__global__ __launch_bounds__(128) void mer_loss(const float* __restrict__ lp,
                                                const int* __restrict__ dist,
                                                const int* __restrict__ reflen,
                                                float* __restrict__ out)
{
    const int b = threadIdx.x;  // 0..127
    double M = -1e300;
    for (int s = 0; s < SAMPLES; s++)
        M = fmax(M, (double)lp[b * SAMPLES + s]);
    double se = 0.0, see = 0.0, ser = 0.0;
    const double rl = (double)reflen[b];
    for (int s = 0; s < SAMPLES; s++) {
        double e  = exp((double)lp[b * SAMPLES + s] - M);
        double er = (double)dist[b * SAMPLES + s] / rl;
        se  += e;
        see += er * e;
        ser += er;
    }
    double val = see / se - ser * (1.0 / SAMPLES);

#pragma unroll
    for (int off = 32; off > 0; off >>= 1)
        val += __shfl_down(val, off);

    __shared__ double red[2];
    if ((b & 63) == 0) red[b >> 6] = val;
    __syncthreads();
    if (b == 0) out[0] = (float)((red[0] + red[1]) / (double)(BATCH * SAMPLES));
}

extern "C" void kernel_launch(void* const* d_in, const int* in_sizes, int n_in,
                              void* d_out, int out_size, void* d_ws, size_t ws_size,
                              hipStream_t stream)
{
    const float* lp  = (const float*)d_in[0];
    const int*   ref = (const int*)d_in[1];
    const int*   hyp = (const int*)d_in[2];

    int* dist   = (int*)d_ws;          // NSEQ ints
    int* reflen = dist + NSEQ;         // BATCH ints
    float* out  = (float*)d_out;

    mer_edit<<<BATCH, 64, 0, stream>>>(ref, hyp, dist, reflen);
    mer_loss<<<1, 128, 0, stream>>>(lp, dist, reflen, out);
}

// Round 2
// 151.528 us; speedup vs baseline: 1.0994x; 1.0994x over previous
//
#include <hip/hip_runtime.h>
#include <stdint.h>

// MinimumErrorRateLoss: unit-cost Levenshtein via Myers/Hyyrö bit-parallel DP,
// fused softmax-weighted centered error-rate mean.
//
// Layout (fixed problem size):
//   log_probs: (128, 64) f32      -> lp[b*64+s]
//   ref:       (256, 128) i32     -> ref[j*128+b]   (shared across samples)
//   hyp:       (256, 128, 64) i32 -> hyp[t*8192 + b*64 + s]
//   out:       scalar f32
// EOS = 0, INCLUDE_EOS -> len = first-EOS-idx + 1, else T.
//
// R1 analysis: 956 cyc/step, VALUBusy 7%, occupancy 1.4% -> per-step global
// token load latency (~600-900 cyc) fully exposed with 1 wave/SIMD.
// Fix: stage hyp slab in LDS (u16, 32 KB) so the serial loop touches only
// LDS; fuse the loss reduction into the edit kernel (wave shfl, f64).

#define BATCH   128
#define SAMPLES 64
#define RLEN    256
#define HLEN    256
#define NSEQ    (BATCH*SAMPLES)
#define NTOK    1000
#define NW      4          // 256 ref positions / 64 bits

typedef unsigned long long u64;

// One block per batch element b (64 threads = 1 wave, one sample per lane).
__global__ __launch_bounds__(64) void mer_edit(const float* __restrict__ lp,
                                               const int* __restrict__ ref,
                                               const int* __restrict__ hyp,
                                               double* __restrict__ partial)
{
    const int b   = blockIdx.x;    // 0..127
    const int tid = threadIdx.x;   // 0..63

    __shared__ u64 pm[NTOK * NW];               // 32000 B
    __shared__ unsigned short ht[HLEN * SAMPLES]; // 32768 B  (tokens < 1000 fit u16)

    // ---- stage this block's hyp slab into LDS (coalesced int4 loads) ----
    {
        const int s4 = (tid & 15) * 4;   // sample offset, int4 granularity
        const int r0 = tid >> 4;         // row within 4-row group
#pragma unroll 16
        for (int it = 0; it < 64; it++) {
            int t = it * 4 + r0;
            int4 v = *(const int4*)(hyp + t * NSEQ + b * SAMPLES + s4);
            ushort4 w;
            w.x = (unsigned short)v.x; w.y = (unsigned short)v.y;
            w.z = (unsigned short)v.z; w.w = (unsigned short)v.w;
            *(ushort4*)&ht[t * SAMPLES + s4] = w;
        }
    }

    // ---- ref_len: first EOS in ref column b (wave-reduce min) ----
    int firsteos = RLEN;
#pragma unroll
    for (int k = 0; k < RLEN / 64; k++) {
        int j = tid + 64 * k;
        if (ref[j * BATCH + b] == 0) firsteos = min(firsteos, j);
    }
#pragma unroll
    for (int off = 32; off > 0; off >>= 1)
        firsteos = min(firsteos, __shfl_down(firsteos, off));
    firsteos = __shfl(firsteos, 0);
    const int m = (firsteos < RLEN) ? (firsteos + 1) : RLEN;  // 1..256

    // ---- build PM table in LDS ----
    for (int i = tid; i < NTOK * NW; i += 64) pm[i] = 0ull;
    __syncthreads();
    for (int j = tid; j < m; j += 64) {
        int tk = ref[j * BATCH + b];
        atomicOr((unsigned long long*)&pm[tk * NW + (j >> 6)], 1ull << (j & 63));
    }
    __syncthreads();

    // ---- Myers/Hyyrö bit-parallel Levenshtein ----
    const int sw = (m - 1) >> 6, sb = (m - 1) & 63;  // score bit (block-uniform)
    u64 VP[NW] = {~0ull, ~0ull, ~0ull, ~0ull};
    u64 VN[NW] = {0, 0, 0, 0};
    int  score = m;
    bool done  = false;

    // pipeline: token read 2 steps ahead (LDS), Eq read 1 step ahead (LDS)
    int tokA = ht[0 * SAMPLES + tid];
    int tokB = ht[1 * SAMPLES + tid];
    u64 EqA[NW];
    {
        const u64* p = &pm[tokA * NW];
        EqA[0] = p[0]; EqA[1] = p[1]; EqA[2] = p[2]; EqA[3] = p[3];
    }

    for (int t = 0; t < HLEN; t++) {
        int t2   = (t + 2 < HLEN) ? (t + 2) : (HLEN - 1);
        int tokC = ht[t2 * SAMPLES + tid];
        u64 EqB[NW];
        {
            const u64* p = &pm[tokB * NW];
            EqB[0] = p[0]; EqB[1] = p[1]; EqB[2] = p[2]; EqB[3] = p[3];
        }

        if (!done) {
            u64 addc = 0, hpc = 1ull, hnc = 0;  // hpc=1: D[0][j]=j boundary
            int sdelta = 0;
#pragma unroll
            for (int w = 0; w < NW; w++) {
                u64 eq = EqA[w], vp = VP[w], vn = VN[w];
                u64 x  = eq & vp;
                u64 s1 = x + vp;
                u64 c0 = (u64)(s1 < x);
                u64 s2 = s1 + addc;
                u64 c1 = (u64)(s2 < s1);
                addc   = c0 | c1;
                u64 D0 = (s2 ^ vp) | eq | vn;
                u64 HP = vn | ~(D0 | vp);
                u64 HN = vp & D0;
                if (w == sw)  // uniform branch (m is block-uniform)
                    sdelta = (int)((HP >> sb) & 1ull) - (int)((HN >> sb) & 1ull);
                u64 nhpc = HP >> 63, nhnc = HN >> 63;
                u64 HPs = (HP << 1) | hpc, HNs = (HN << 1) | hnc;
                hpc = nhpc; hnc = nhnc;
                VP[w] = HNs | ~(D0 | HPs);
                VN[w] = HPs & D0;
            }
            score += sdelta;
            if (tokA == 0) done = true;  // processed first EOS -> freeze
        }

        EqA[0] = EqB[0]; EqA[1] = EqB[1]; EqA[2] = EqB[2]; EqA[3] = EqB[3];
        tokA = tokB; tokB = tokC;
    }

    // ---- fused per-batch loss: sum_s (er - mean_er)*softmax
    //      = dot(er,p)/sumexp - mean_er  (since sum p = 1). f64 for accuracy.
    double er = (double)score / (double)m;
    double x  = (double)lp[b * SAMPLES + tid];
    double mx = x;
#pragma unroll
    for (int off = 32; off > 0; off >>= 1)
        mx = fmax(mx, __shfl_xor(mx, off));
    double e = exp(x - mx);
    double se = e, see = er * e, ser = er;
#pragma unroll
    for (int off = 32; off > 0; off >>= 1) {
        se  += __shfl_xor(se,  off);
        see += __shfl_xor(see, off);
        ser += __shfl_xor(ser, off);
    }
    if (tid == 0) partial[b] = see / se - ser * (1.0 / SAMPLES);
}

// 1 block, 64 threads: sum 128 per-batch partials, scale, write scalar.
__global__ __launch_bounds__(64) void mer_final(const double* __restrict__ partial,
                                                float* __restrict__ out)
{
    const int tid = threadIdx.x;
    double v = partial[tid] + partial[tid + 64];
#pragma unroll
    for (int off = 32; off > 0; off >>= 1)
        v += __shfl_xor(v, off);
    if (tid == 0) out[0] = (float)(v / (double)(BATCH * SAMPLES));
}

extern "C" void kernel_launch(void* const* d_in, const int* in_sizes, int n_in,
                              void* d_out, int out_size, void* d_ws, size_t ws_size,
                              hipStream_t stream)
{
    const float* lp  = (const float*)d_in[0];
    const int*   ref = (const int*)d_in[1];
    const int*   hyp = (const int*)d_in[2];

    double* partial = (double*)d_ws;   // 128 doubles
    float*  out     = (float*)d_out;

    mer_edit<<<BATCH, 64, 0, stream>>>(lp, ref, hyp, partial);
    mer_final<<<1, 64, 0, stream>>>(partial, out);
}

// Round 3
// 150.223 us; speedup vs baseline: 1.1090x; 1.0087x over previous
//
#include <hip/hip_runtime.h>
#include <stdint.h>

// MinimumErrorRateLoss: unit-cost Levenshtein via Myers/Hyyrö bit-parallel DP,
// word-SPLIT ACROSS 4 WAVES (systolic pipeline), fused f64 loss epilogue.
//
// Layout (fixed problem size):
//   log_probs: (128, 64) f32      -> lp[b*64+s]
//   ref:       (256, 128) i32     -> ref[j*128+b]   (shared across samples)
//   hyp:       (256, 128, 64) i32 -> hyp[t*8192 + b*64 + s]
//   out:       scalar f32
// EOS = 0, INCLUDE_EOS -> len = first-EOS-idx + 1, else T.
//
// R2 analysis: issue-bound on 1 wave/CU-SIMD (VALUBusy 62% per active SIMD,
// ~930 cyc/step, 128 waves on 1024 SIMDs). Fix: block = 4 waves; wave w owns
// u64-word w of the 256-bit Myers state for all 64 samples (one sample/lane).
// Inter-word carries (add carry, HP/HN shift-out) are 1 bit/sample/word ->
// packed with __ballot, passed wave w -> w+1 through double-buffered LDS with
// a skewed schedule: at phase P, wave w does DP step t = P - w using carries
// wave w-1 produced at phase P-1. One __syncthreads per phase.

#define BATCH   128
#define SAMPLES 64
#define RLEN    256
#define HLEN    256
#define NSEQ    (BATCH*SAMPLES)
#define NTOK    1000
#define NW      4          // 256 ref positions / 64 bits = 4 words = 4 waves

typedef unsigned long long u64;
typedef unsigned __int128  u128;

__global__ __launch_bounds__(256) void mer_edit(const float* __restrict__ lp,
                                                const int* __restrict__ ref,
                                                const int* __restrict__ hyp,
                                                double* __restrict__ partial)
{
    const int b    = blockIdx.x;     // batch element
    const int tid  = threadIdx.x;    // 0..255
    const int w    = tid >> 6;       // word / wave index 0..3
    const int lane = tid & 63;       // sample index 0..63

    __shared__ u64 pm[NTOK * NW];                 // 32000 B  Eq bit-table
    __shared__ unsigned short ht[HLEN * SAMPLES]; // 32768 B  hyp tokens (u16)
    __shared__ u64 cb[2][NW][4];                  //   256 B  carry ballots (dbuf)
    __shared__ int scores[SAMPLES];               //   256 B
    __shared__ int m_sh;

    if (tid == 0) m_sh = RLEN;

    // ---- zero PM (4000 u64 / 256 threads) ----
    for (int i = tid; i < NTOK * NW; i += 256) pm[i] = 0ull;

    // ---- stage hyp slab: 256x64 tokens = 4096 int4, 16 per thread ----
#pragma unroll
    for (int it = 0; it < 16; it++) {
        int idx = it * 256 + tid;         // int4 index
        int t   = idx >> 4;
        int s4  = (idx & 15) * 4;
        int4 v  = *(const int4*)(hyp + t * NSEQ + b * SAMPLES + s4);
        ushort4 u;
        u.x = (unsigned short)v.x; u.y = (unsigned short)v.y;
        u.z = (unsigned short)v.z; u.w = (unsigned short)v.w;
        *(ushort4*)&ht[t * SAMPLES + s4] = u;
    }

    // ---- ref column: one token per thread (j = tid) ----
    const int rt = ref[tid * BATCH + b];
    __syncthreads();                      // m_sh init + pm zero complete
    if (rt == 0) atomicMin(&m_sh, tid);
    __syncthreads();
    const int m = (m_sh < RLEN) ? (m_sh + 1) : RLEN;   // ref_len, 1..256
    if (tid < m)
        atomicOr((unsigned long long*)&pm[rt * NW + (tid >> 6)],
                 1ull << (tid & 63));
    __syncthreads();                      // pm + ht ready

    // ---- systolic Myers: wave w owns word w ----
    const int sw = (m - 1) >> 6, sb = (m - 1) & 63;    // score bit location
    u64  VP = ~0ull, VN = 0ull;
    int  score = m;
    bool done  = false;

    // prime 1-step prefetch for this wave's t = 0
    int tokCur = ht[0 * SAMPLES + lane];
    u64 EqCur  = pm[tokCur * NW + w];

    for (int P = 0; P < HLEN + NW - 1; ++P) {
        __syncthreads();                  // publish phase P-1 carries
        const int t = P - w;              // wave-uniform
        if (t >= 0 && t < HLEN) {
            // prefetch next step's token+Eq (consumed next phase)
            int tn      = (t + 1 < HLEN) ? (t + 1) : t;
            int tokNext = ht[tn * SAMPLES + lane];
            u64 EqNext  = pm[tokNext * NW + w];

            // carries in from word w-1 (same DP step, produced last phase)
            u64 cinb, hpinb, hninb;
            if (w > 0) {
                const u64* src = cb[(P & 1) ^ 1][w - 1];
                cinb  = (src[0] >> lane) & 1ull;
                hpinb = (src[1] >> lane) & 1ull;
                hninb = (src[2] >> lane) & 1ull;
            } else {
                cinb = 0ull; hpinb = 1ull; hninb = 0ull;  // D[0][j]=j boundary
            }

            const u64 eq = EqCur, vp = VP, vn = VN;
            const u64 x  = eq & vp;
            const u128 S = (u128)x + vp + cinb;           // word add + carry-in
            const u64 s2   = (u64)S;
            const u64 cout = (u64)(S >> 64);              // carry-out (0/1)
            const u64 D0 = (s2 ^ vp) | eq | vn;
            const u64 HP = vn | ~(D0 | vp);
            const u64 HN = vp & D0;
            const u64 HPs = (HP << 1) | hpinb;
            const u64 HNs = (HN << 1) | hninb;
            const u64 nVP = HNs | ~(D0 | HPs);
            const u64 nVN = HPs & D0;

            // carries out to word w+1 (ballot-packed across the 64 samples)
            u64 bc  = __ballot(cout != 0ull);
            u64 bhp = __ballot((HP >> 63) & 1ull);
            u64 bhn = __ballot((HN >> 63) & 1ull);
            if (lane < 3)
                cb[P & 1][w][lane] = (lane == 0) ? bc : ((lane == 1) ? bhp : bhn);

            if (!done) {                  // per-lane freeze after hyp EOS step
                VP = nVP; VN = nVN;
                if (w == sw)              // block-uniform branch
                    score += (int)((HP >> sb) & 1ull) - (int)((HN >> sb) & 1ull);
                if (tokCur == 0) done = true;
            }
            tokCur = tokNext; EqCur = EqNext;
        }
    }

    if (w == sw) scores[lane] = score;    // score word holds the distances
    __syncthreads();

    // ---- fused per-batch loss on wave 0 (f64):
    //      sum_s (er - mean_er)*softmax = dot(er,p)/sumexp - mean_er
    if (w == 0) {
        double er = (double)scores[lane] / (double)m;
        double x  = (double)lp[b * SAMPLES + lane];
        double mx = x;
#pragma unroll
        for (int off = 32; off > 0; off >>= 1)
            mx = fmax(mx, __shfl_xor(mx, off));
        double e = exp(x - mx);
        double se = e, see = er * e, ser = er;
#pragma unroll
        for (int off = 32; off > 0; off >>= 1) {
            se  += __shfl_xor(se,  off);
            see += __shfl_xor(see, off);
            ser += __shfl_xor(ser, off);
        }
        if (lane == 0) partial[b] = see / se - ser * (1.0 / SAMPLES);
    }
}

// 1 block, 64 threads: sum 128 per-batch partials, scale, write scalar.
__global__ __launch_bounds__(64) void mer_final(const double* __restrict__ partial,
                                                float* __restrict__ out)
{
    const int tid = threadIdx.x;
    double v = partial[tid] + partial[tid + 64];
#pragma unroll
    for (int off = 32; off > 0; off >>= 1)
        v += __shfl_xor(v, off);
    if (tid == 0) out[0] = (float)(v / (double)(BATCH * SAMPLES));
}

extern "C" void kernel_launch(void* const* d_in, const int* in_sizes, int n_in,
                              void* d_out, int out_size, void* d_ws, size_t ws_size,
                              hipStream_t stream)
{
    const float* lp  = (const float*)d_in[0];
    const int*   ref = (const int*)d_in[1];
    const int*   hyp = (const int*)d_in[2];

    double* partial = (double*)d_ws;   // 128 doubles
    float*  out     = (float*)d_out;

    mer_edit<<<BATCH, 256, 0, stream>>>(lp, ref, hyp, partial);
    mer_final<<<1, 64, 0, stream>>>(partial, out);
}

// Round 4
// 116.302 us; speedup vs baseline: 1.4324x; 1.2917x over previous
//
#include <hip/hip_runtime.h>
#include <stdint.h>

// MinimumErrorRateLoss: unit-cost Levenshtein via Myers/Hyyrö bit-parallel DP.
// R4: word-split WITHIN the wave. lane = (sample%16)*4 + word; carries pass
// lane w -> w+1 via one v_mov_dpp quad_perm (no LDS, no barrier). Skewed
// schedule: at phase P, lane with word w computes DP step t = P - w, consuming
// the carry its neighbor produced (in lockstep) at phase P-1.
//
// Layout (fixed problem size):
//   log_probs: (128, 64) f32      -> lp[b*64+s]
//   ref:       (256, 128) i32     -> ref[j*128+b]   (shared across samples)
//   hyp:       (256, 128, 64) i32 -> hyp[t*8192 + b*64 + s]
//   out:       scalar f32
// EOS = 0, INCLUDE_EOS -> len = first-EOS-idx + 1, else T.
//
// R3 analysis: 834 cyc/phase; ~280 issue, ~550 stall = per-phase __syncthreads
// + LDS carry round-trip with 1 wave/SIMD (nothing to hide it). This version
// has ZERO barriers in the main loop; per-phase cost ~ issue (~130 cyc).

#define BATCH   128
#define SAMPLES 64
#define RLEN    256
#define HLEN    256
#define NSEQ    (BATCH*SAMPLES)
#define NTOK    1000
#define NW      4          // 256 ref positions / 64 bits

typedef unsigned long long u64;
typedef unsigned __int128  u128;

// quad_perm:[0,0,1,2] -> lane j (within each group of 4) reads lane j-1.
__device__ __forceinline__ int quad_up(int x) {
    return __builtin_amdgcn_mov_dpp(x, 0x90, 0xf, 0xf, true);
}

__global__ __launch_bounds__(256) void mer_edit(const float* __restrict__ lp,
                                                const int* __restrict__ ref,
                                                const int* __restrict__ hyp,
                                                double* __restrict__ partial)
{
    const int b    = blockIdx.x;     // batch element
    const int tid  = threadIdx.x;    // 0..255
    const int wave = tid >> 6;       // 0..3 (independent after prologue)
    const int lane = tid & 63;
    const int w    = lane & 3;       // Myers word index 0..3
    const int s    = wave * 16 + (lane >> 2);   // sample 0..63

    __shared__ u64 pm[NTOK * NW];                 // 32000 B  Eq bit-table
    __shared__ unsigned short ht[HLEN * SAMPLES]; // 32768 B  hyp tokens (u16)
    __shared__ int scores[SAMPLES];               //   256 B
    __shared__ int m_sh;

    if (tid == 0) m_sh = RLEN;

    // ---- zero PM (4000 u64 / 256 threads) ----
    for (int i = tid; i < NTOK * NW; i += 256) pm[i] = 0ull;

    // ---- stage hyp slab: 256x64 tokens = 4096 int4, 16 per thread ----
#pragma unroll
    for (int it = 0; it < 16; it++) {
        int idx = it * 256 + tid;         // int4 index
        int t   = idx >> 4;
        int s4  = (idx & 15) * 4;
        int4 v  = *(const int4*)(hyp + t * NSEQ + b * SAMPLES + s4);
        ushort4 u;
        u.x = (unsigned short)v.x; u.y = (unsigned short)v.y;
        u.z = (unsigned short)v.z; u.w = (unsigned short)v.w;
        *(ushort4*)&ht[t * SAMPLES + s4] = u;
    }

    // ---- ref column: one token per thread (j = tid) ----
    const int rt = ref[tid * BATCH + b];
    __syncthreads();                      // m_sh init + pm zero complete
    if (rt == 0) atomicMin(&m_sh, tid);
    __syncthreads();
    const int m = (m_sh < RLEN) ? (m_sh + 1) : RLEN;   // ref_len, 1..256
    if (tid < m)
        atomicOr((unsigned long long*)&pm[rt * NW + (tid >> 6)],
                 1ull << (tid & 63));
    __syncthreads();                      // pm + ht ready; no more barriers

    // ---- systolic-in-wave Myers: lane owns (sample s, word w) ----
    const int  sw   = (m - 1) >> 6, sb = (m - 1) & 63;  // score bit location
    const bool isW0 = (w == 0);
    const bool isSW = (w == sw);

    u64  VP = ~0ull, VN = 0ull;
    int  score = m;
    bool done  = false;

    // pipeline prime: tokens 3 ahead, Eq 2 ahead (t starts at -w)
    const int tp0 = (0 - w) < 0 ? 0 : (0 - w);          // clamp(-w)
    const int tp1 = (1 - w) < 0 ? 0 : (1 - w);
    const int tp2 = (2 - w) < 0 ? 0 : (2 - w);
    int tokA = ht[tp0 * SAMPLES + s];
    int tokB = ht[tp1 * SAMPLES + s];
    int tokC = ht[tp2 * SAMPLES + s];
    u64 EqA  = pm[tokA * NW + w];
    u64 EqB  = pm[tokB * NW + w];

    int out_pkd = 0;   // packed (cout, hp63, hn63) from my previous phase

    for (int P = 0; P < HLEN + NW - 1; ++P) {
        const int t  = P - w;                            // per-lane step
        const int t3 = (t + 3 < HLEN) ? (t + 3) : (HLEN - 1);  // >= 0 always

        // prefetch (consumed 2-3 phases later; LDS latency fully covered)
        int tokD = ht[t3 * SAMPLES + s];
        u64 EqC  = pm[tokC * NW + w];

        // carries from word w-1 (its phase P-1 output), one DPP
        const int inp  = quad_up(out_pkd);
        const u64 cin  = isW0 ? 0ull : (u64)(inp & 1);
        const u64 hpin = isW0 ? 1ull : (u64)((inp >> 1) & 1);  // D[0][j]=j
        const u64 hnin = isW0 ? 0ull : (u64)((inp >> 2) & 1);

        const u64 eq = EqA, vp = VP, vn = VN;
        const u64 x  = eq & vp;
        const u128 S = (u128)x + vp + cin;
        const u64 s2   = (u64)S;
        const u64 cout = (u64)(S >> 64);
        const u64 D0 = (s2 ^ vp) | eq | vn;
        const u64 HP = vn | ~(D0 | vp);
        const u64 HN = vp & D0;
        const u64 HPs = (HP << 1) | hpin;
        const u64 HNs = (HN << 1) | hnin;
        const u64 nVP = HNs | ~(D0 | HPs);
        const u64 nVN = HPs & D0;

        out_pkd = (int)cout | ((int)(HP >> 63) << 1) | ((int)(HN >> 63) << 2);

        const bool valid = (t >= 0) && (t < HLEN) && !done;
        if (valid) {
            VP = nVP; VN = nVN;
            if (isSW)
                score += (int)((HP >> sb) & 1ull) - (int)((HN >> sb) & 1ull);
            if (tokA == 0) done = true;   // processed first hyp EOS -> freeze
        }

        tokA = tokB; tokB = tokC; tokC = tokD;
        EqA  = EqB;  EqB  = EqC;
    }

    if (isSW) scores[s] = score;          // score-bit word holds the distance
    __syncthreads();

    // ---- fused per-batch loss on wave 0 (f64):
    //      sum_s (er - mean_er)*softmax = dot(er,p)/sumexp - mean_er
    if (wave == 0) {
        double er = (double)scores[lane] / (double)m;
        double x  = (double)lp[b * SAMPLES + lane];
        double mx = x;
#pragma unroll
        for (int off = 32; off > 0; off >>= 1)
            mx = fmax(mx, __shfl_xor(mx, off));
        double e = exp(x - mx);
        double se = e, see = er * e, ser = er;
#pragma unroll
        for (int off = 32; off > 0; off >>= 1) {
            se  += __shfl_xor(se,  off);
            see += __shfl_xor(see, off);
            ser += __shfl_xor(ser, off);
        }
        if (lane == 0) partial[b] = see / se - ser * (1.0 / SAMPLES);
    }
}

// 1 block, 64 threads: sum 128 per-batch partials, scale, write scalar.
__global__ __launch_bounds__(64) void mer_final(const double* __restrict__ partial,
                                                float* __restrict__ out)
{
    const int tid = threadIdx.x;
    double v = partial[tid] + partial[tid + 64];
#pragma unroll
    for (int off = 32; off > 0; off >>= 1)
        v += __shfl_xor(v, off);
    if (tid == 0) out[0] = (float)(v / (double)(BATCH * SAMPLES));
}

extern "C" void kernel_launch(void* const* d_in, const int* in_sizes, int n_in,
                              void* d_out, int out_size, void* d_ws, size_t ws_size,
                              hipStream_t stream)
{
    const float* lp  = (const float*)d_in[0];
    const int*   ref = (const int*)d_in[1];
    const int*   hyp = (const int*)d_in[2];

    double* partial = (double*)d_ws;   // 128 doubles
    float*  out     = (float*)d_out;

    mer_edit<<<BATCH, 256, 0, stream>>>(lp, ref, hyp, partial);
    mer_final<<<1, 64, 0, stream>>>(partial, out);
}

// Round 5
// 103.994 us; speedup vs baseline: 1.6020x; 1.1184x over previous
//
#include <hip/hip_runtime.h>
#include <stdint.h>

// MinimumErrorRateLoss: unit-cost Levenshtein via Myers/Hyyrö bit-parallel DP.
// R5: 8-way u32 word split, grid 256 (full chip). Block (b,half) = 32 samples
// x 8 words = 256 threads; lane = si*8 + w. Carry (add-c, HP/HN shift-out)
// passes lane w -> w+1 via one v_mov_dpp row_shr:1 (w==0 lanes overridden
// with the DP boundary). Skewed schedule: at phase P, word-lane w computes
// DP step t = P - w. No barriers in the main loop.
//
// R4 analysis: 583 cyc/phase = ~213 issue (u64 emulation ~100 instrs) + ~370
// exposed dep-chain latency at 1 wave/SIMD with HALF the CUs idle (512 waves
// on 1024 SIMDs). u32 split halves issue width and doubles CU coverage.
// LDS strides padded (pm 9 u32, ht 36 u16) to break power-of-2 bank aliasing.
//
// Layout (fixed problem size):
//   log_probs: (128, 64) f32      -> lp[b*64+s]
//   ref:       (256, 128) i32     -> ref[j*128+b]   (shared across samples)
//   hyp:       (256, 128, 64) i32 -> hyp[t*8192 + b*64 + s]
//   out:       scalar f32
// EOS = 0, INCLUDE_EOS -> len = first-EOS-idx + 1, else T.

#define BATCH   128
#define SAMPLES 64
#define RLEN    256
#define HLEN    256
#define NSEQ    (BATCH*SAMPLES)
#define NTOK    1000
#define NWW     8          // 256 ref positions / 32 bits
#define SPB     32         // samples per block
#define PMSTR   9          // pm row stride in u32 (padded: 8 -> 9)
#define HTSTR   36         // ht row stride in u16 (padded: 32 -> 36)

typedef unsigned long long u64;
typedef unsigned int       u32;

// DPP row_shr:1 -> lane i reads lane i-1 (rows of 16); bound lanes get 0.
__device__ __forceinline__ int row_shr1(int x) {
    return __builtin_amdgcn_mov_dpp(x, 0x111, 0xf, 0xf, true);
}

__global__ __launch_bounds__(256) void mer_edit(const int* __restrict__ ref,
                                                const int* __restrict__ hyp,
                                                int* __restrict__ scores,
                                                int* __restrict__ reflen)
{
    const int blk  = blockIdx.x;      // 0..255
    const int b    = blk >> 1;        // batch element
    const int half = blk & 1;         // sample half (0: s 0..31, 1: s 32..63)
    const int tid  = threadIdx.x;     // 0..255
    const int lane = tid & 63;
    const int w    = lane & 7;                         // u32 word 0..7
    const int sl   = (tid >> 6) * 8 + (lane >> 3);     // local sample 0..31

    __shared__ __align__(16) u32 pm[NTOK * PMSTR];            // 36000 B
    __shared__ __align__(16) unsigned short ht[HLEN * HTSTR]; // 18432 B
    __shared__ int m_sh;

    if (tid == 0) m_sh = RLEN;

    // ---- zero PM (9000 u32 = 2250 int4) ----
    for (int i = tid; i < (NTOK * PMSTR) / 4; i += 256)
        ((int4*)pm)[i] = int4{0, 0, 0, 0};

    // ---- stage this block's 32-sample hyp slab: 2048 int4, 8/thread ----
#pragma unroll
    for (int it = 0; it < 8; it++) {
        int idx = it * 256 + tid;     // int4 index
        int t   = idx >> 3;
        int s4  = (idx & 7) * 4;
        int4 v  = *(const int4*)(hyp + t * NSEQ + b * SAMPLES + half * SPB + s4);
        ushort4 u;
        u.x = (unsigned short)v.x; u.y = (unsigned short)v.y;
        u.z = (unsigned short)v.z; u.w = (unsigned short)v.w;
        *(ushort4*)&ht[t * HTSTR + s4] = u;
    }

    // ---- ref column: one token per thread (j = tid) ----
    const int rt = ref[tid * BATCH + b];
    __syncthreads();                  // m_sh + pm zero done
    if (rt == 0) atomicMin(&m_sh, tid);
    __syncthreads();
    const int m = (m_sh < RLEN) ? (m_sh + 1) : RLEN;   // ref_len, 1..256
    if (tid < m)
        atomicOr(&pm[rt * PMSTR + (tid >> 5)], 1u << (tid & 31));
    __syncthreads();                  // pm + ht ready; no more barriers

    // ---- systolic-in-wave Myers, u32 words ----
    const int  sw   = (m - 1) >> 5, sb = (m - 1) & 31;  // score bit location
    const bool isW0 = (w == 0);
    const bool isSW = (w == sw);

    u32  VP = ~0u, VN = 0u;
    int  score = m;
    bool done  = false;

    // pipeline prime: tokens 3 ahead, Eq 2 ahead (t starts at -w; clamp)
    int tokA, tokB, tokC;
    u32 EqA, EqB;
    {
        int p0 = (0 - w) < 0 ? 0 : (0 - w);
        int p1 = (1 - w) < 0 ? 0 : (1 - w);
        int p2 = (2 - w) < 0 ? 0 : (2 - w);
        tokA = ht[p0 * HTSTR + sl];
        tokB = ht[p1 * HTSTR + sl];
        tokC = ht[p2 * HTSTR + sl];
        EqA  = pm[tokA * PMSTR + w];
        EqB  = pm[tokB * PMSTR + w];
    }

    int out_pkd = 0;   // packed (cout, hp31, hn31) from my previous phase
    int t = -w;        // this lane's current DP step

    for (int P = 0; P < HLEN + NWW - 1; ++P, ++t) {
        int t3 = t + 3;
        t3 = (t3 < 0) ? 0 : ((t3 > HLEN - 1) ? (HLEN - 1) : t3);

        // prefetch (consumed 2-3 phases later; LDS latency covered)
        int tokD = ht[t3 * HTSTR + sl];
        u32 EqC  = pm[tokC * PMSTR + w];

        // carries from word w-1 (its previous-phase output), one DPP
        int inp = row_shr1(out_pkd);
        if (isW0) inp = 2;            // cin=0, hpin=1 (D[0][j]=j), hnin=0
        const u32 cin  = (u32)(inp & 1);
        const u32 hpin = (u32)((inp >> 1) & 1);
        const u32 hnin = (u32)((inp >> 2) & 1);

        const u32 eq = EqA, vp = VP, vn = VN;
        const u32 x  = eq & vp;
        const u64 S  = (u64)x + vp + cin;
        const u32 s2   = (u32)S;
        const u32 cout = (u32)(S >> 32);
        const u32 D0 = (s2 ^ vp) | eq | vn;
        const u32 HP = vn | ~(D0 | vp);
        const u32 HN = vp & D0;
        const u32 HPs = (HP << 1) | hpin;
        const u32 HNs = (HN << 1) | hnin;
        const u32 nVP = HNs | ~(D0 | HPs);
        const u32 nVN = HPs & D0;

        out_pkd = (int)(cout | ((HP >> 31) << 1) | ((HN >> 31) << 2));

        const bool valid = (t >= 0) && (t < HLEN) && !done;
        if (valid) {
            VP = nVP; VN = nVN;
            if (isSW)
                score += (int)((HP >> sb) & 1u) - (int)((HN >> sb) & 1u);
            if (tokA == 0) done = true;   // processed first hyp EOS -> freeze
        }

        tokA = tokB; tokB = tokC; tokC = tokD;
        EqA  = EqB;  EqB  = EqC;
    }

    if (isSW) scores[b * SAMPLES + half * SPB + sl] = score;
    if (half == 0 && tid == 0) reflen[b] = m;
}

// Grid 128 x 64 threads: per-batch f64 loss partial.
//   sum_s (er - mean_er)*softmax = dot(er,p)/sumexp - mean_er  (sum p = 1)
__global__ __launch_bounds__(64) void mer_loss(const float* __restrict__ lp,
                                               const int* __restrict__ scores,
                                               const int* __restrict__ reflen,
                                               double* __restrict__ partial)
{
    const int b = blockIdx.x, s = threadIdx.x;
    double er = (double)scores[b * SAMPLES + s] / (double)reflen[b];
    double x  = (double)lp[b * SAMPLES + s];
    double mx = x;
#pragma unroll
    for (int off = 32; off > 0; off >>= 1)
        mx = fmax(mx, __shfl_xor(mx, off));
    double e = exp(x - mx);
    double se = e, see = er * e, ser = er;
#pragma unroll
    for (int off = 32; off > 0; off >>= 1) {
        se  += __shfl_xor(se,  off);
        see += __shfl_xor(see, off);
        ser += __shfl_xor(ser, off);
    }
    if (s == 0) partial[b] = see / se - ser * (1.0 / SAMPLES);
}

// 1 block, 64 threads: sum 128 per-batch partials, scale, write scalar.
__global__ __launch_bounds__(64) void mer_final(const double* __restrict__ partial,
                                                float* __restrict__ out)
{
    const int tid = threadIdx.x;
    double v = partial[tid] + partial[tid + 64];
#pragma unroll
    for (int off = 32; off > 0; off >>= 1)
        v += __shfl_xor(v, off);
    if (tid == 0) out[0] = (float)(v / (double)(BATCH * SAMPLES));
}

extern "C" void kernel_launch(void* const* d_in, const int* in_sizes, int n_in,
                              void* d_out, int out_size, void* d_ws, size_t ws_size,
                              hipStream_t stream)
{
    const float* lp  = (const float*)d_in[0];
    const int*   ref = (const int*)d_in[1];
    const int*   hyp = (const int*)d_in[2];

    double* partial = (double*)d_ws;                   // 128 f64
    int*    scores  = (int*)(partial + BATCH);         // 8192 i32
    int*    reflen  = scores + NSEQ;                   // 128 i32
    float*  out     = (float*)d_out;

    mer_edit<<<2 * BATCH, 256, 0, stream>>>(ref, hyp, scores, reflen);
    mer_loss<<<BATCH, 64, 0, stream>>>(lp, scores, reflen, partial);
    mer_final<<<1, 64, 0, stream>>>(partial, out);
}